// Round 10
// baseline (245.559 us; speedup 1.0000x reference)
//
#include <hip/hip_runtime.h>

#define NEG_SLOPE 0.2f
#define EPSF 1e-16f
#define ABLK 512
#define SHIFT 8
#define SWZ(e)  (((e) << 5) | 0x18)   // src = (lane&0x18)|e  (groups of 8)
#define SWZ4(e) (((e) << 5) | 0x1C)   // src = (lane&0x1C)|e  (groups of 4)

using short8 = __attribute__((ext_vector_type(8))) short;
using f32x4  = __attribute__((ext_vector_type(4))) float;

__device__ __forceinline__ float lrelu_exp(float a) {
    a = (a > 0.f) ? a : NEG_SLOPE * a;
    return __expf(a);
}

__device__ __forceinline__ unsigned short f2bf(float f) {   // RNE
    unsigned u = __float_as_uint(f);
    u += 0x7fff + ((u >> 16) & 1);
    return (unsigned short)(u >> 16);
}

__device__ __forceinline__ float bf2f(unsigned short b) {
    return __uint_as_float(((unsigned)b) << 16);
}

__device__ __forceinline__ float bf_lo(unsigned pv) { return __uint_as_float(pv << 16); }
__device__ __forceinline__ float bf_hi(unsigned pv) { return __uint_as_float(pv & 0xffff0000u); }

template <int PAT>
__device__ __forceinline__ float swz_f(float v) {
    return __uint_as_float((unsigned)__builtin_amdgcn_ds_swizzle(__float_as_int(v), PAT));
}
template <int PAT>
__device__ __forceinline__ int swz_i(int v) {
    return __builtin_amdgcn_ds_swizzle(v, PAT);
}

// ---- fused: bhist (blocks [0,ABLK)) + W-prep (blocks [ABLK, ABLK+88)) --------
__global__ __launch_bounds__(256) void k_ph(const int* __restrict__ ei, int E, int N,
                                            int NBK, int* __restrict__ H,
                                            const float* __restrict__ W1,
                                            const float* __restrict__ W2,
                                            unsigned short* __restrict__ W1s,
                                            unsigned short* __restrict__ W2s) {
    __shared__ int hist[512];
    const int t = threadIdx.x;
    if (blockIdx.x < ABLK) {
        // ---------------- bhist ----------------
        for (int i = t; i < NBK; i += 256) hist[i] = 0;
        __syncthreads();
        const int Et = E + N;
        for (int e = blockIdx.x * 256 + t; e < Et; e += ABLK * 256) {
            int d = (e < E) ? ei[E + e] : (e - E);
            atomicAdd(&hist[d >> SHIFT], 1);
        }
        __syncthreads();
        for (int i = t; i < NBK; i += 256)
            H[(size_t)i * ABLK + blockIdx.x] = hist[i];
        return;
    }
    // ---------------- prep: W1/W2 -> MFMA fragment-linear bf16 hi/lo ----------
    const int tid = (blockIdx.x - ABLK) * 256 + t;
    if (tid < 16384) {                       // W1: 4kt x 8nt x 64l x 8e
        const int e  = tid & 7;
        const int l  = (tid >> 3) & 63;
        const int nt = (tid >> 9) & 7;
        const int kt = tid >> 12;
        const int k  = kt * 32 + ((l >> 4) * 8) + e;
        const int n  = nt * 16 + (l & 15);
        const float w = W1[k * 128 + n];
        const unsigned short hi = f2bf(w);
        const unsigned short lo = f2bf(w - bf2f(hi));
        const int idx = (kt * 8 + nt) * 512 + l * 8 + e;
        W1s[idx] = hi;
        W1s[16384 + idx] = lo;
    } else {                                 // W2: 4kt x 3nt x 64l x 8e (pad n>=40)
        const int t2 = tid - 16384;
        if (t2 >= 6144) return;
        const int e  = t2 & 7;
        const int l  = (t2 >> 3) & 63;
        const int g  = t2 >> 9;
        const int nt = g % 3;
        const int kt = g / 3;
        const int k  = kt * 32 + ((l >> 4) * 8) + e;
        const int n  = nt * 16 + (l & 15);
        const float w = (n < 40) ? W2[k * 40 + n] : 0.f;
        const unsigned short hi = f2bf(w);
        const unsigned short lo = f2bf(w - bf2f(hi));
        const int idx = (kt * 3 + nt) * 512 + l * 8 + e;
        W2s[idx] = hi;
        W2s[6144 + idx] = lo;
    }
}

// ---- GEMM1 (MFMA bf16x3) + fused e_src1/e_dst1 from f32 accumulators ---------
__global__ __launch_bounds__(256) void k_mm1(const float* __restrict__ x,
                                             const unsigned short* __restrict__ W1s,
                                             const float* __restrict__ asrc,
                                             const float* __restrict__ adst,
                                             unsigned short* __restrict__ xhb,
                                             float* __restrict__ es,
                                             float* __restrict__ ed, int N) {
    __shared__ unsigned short Bs[32768];     // 64 KB: hi frags then lo frags
    const int t = threadIdx.x;
    for (int i = t; i < 4096; i += 256)
        ((uint4*)Bs)[i] = ((const uint4*)W1s)[i];

    const int wm = t >> 6;
    const int l  = t & 63;
    const int wrow0 = blockIdx.x * 64 + wm * 16;
    const int arow = wrow0 + (l & 15);
    const int rc = (arow < N) ? arow : (N - 1);

    short8 ah[4], al[4];
    #pragma unroll
    for (int kt = 0; kt < 4; ++kt) {
        const float* xp = x + (size_t)rc * 128 + kt * 32 + ((l >> 4) * 8);
        const float4 v0 = ((const float4*)xp)[0];
        const float4 v1 = ((const float4*)xp)[1];
        const float vv[8] = {v0.x, v0.y, v0.z, v0.w, v1.x, v1.y, v1.z, v1.w};
        #pragma unroll
        for (int e = 0; e < 8; ++e) {
            const unsigned short hi = f2bf(vv[e]);
            ((unsigned short*)&ah[kt])[e] = hi;
            ((unsigned short*)&al[kt])[e] = f2bf(vv[e] - bf2f(hi));
        }
    }
    __syncthreads();

    f32x4 acc[8] = {};
    #pragma unroll
    for (int kt = 0; kt < 4; ++kt) {
        #pragma unroll
        for (int nt = 0; nt < 8; ++nt) {
            const short8 bh = *(const short8*)(Bs + (kt * 8 + nt) * 512 + l * 8);
            const short8 bl = *(const short8*)(Bs + 16384 + (kt * 8 + nt) * 512 + l * 8);
            acc[nt] = __builtin_amdgcn_mfma_f32_16x16x32_bf16(ah[kt], bh, acc[nt], 0, 0, 0);
            acc[nt] = __builtin_amdgcn_mfma_f32_16x16x32_bf16(ah[kt], bl, acc[nt], 0, 0, 0);
            acc[nt] = __builtin_amdgcn_mfma_f32_16x16x32_bf16(al[kt], bh, acc[nt], 0, 0, 0);
        }
    }

    // store xh: row = wrow0 + (l>>4)*4 + reg, col = nt*16 + (l&15)
    const int cl = l & 15;
    const int g  = l >> 4;
    const int rbase = wrow0 + g * 4;
    #pragma unroll
    for (int reg = 0; reg < 4; ++reg) {
        const int orow = rbase + reg;
        if (orow < N) {
            #pragma unroll
            for (int nt = 0; nt < 8; ++nt)
                xhb[(size_t)orow * 128 + nt * 16 + cl] = f2bf(acc[nt][reg]);
        }
    }

    // fused e_src/e_dst: head = nt; reduce over the 16-lane col group
    #pragma unroll
    for (int nt = 0; nt < 8; ++nt) {
        const float av = asrc[nt * 16 + cl];
        const float bv = adst[nt * 16 + cl];
        #pragma unroll
        for (int reg = 0; reg < 4; ++reg) {
            float ps = acc[nt][reg] * av;
            float pd = acc[nt][reg] * bv;
            ps += __shfl_xor(ps, 1, 64); ps += __shfl_xor(ps, 2, 64);
            ps += __shfl_xor(ps, 4, 64); ps += __shfl_xor(ps, 8, 64);
            pd += __shfl_xor(pd, 1, 64); pd += __shfl_xor(pd, 2, 64);
            pd += __shfl_xor(pd, 4, 64); pd += __shfl_xor(pd, 8, 64);
            const int row = rbase + reg;
            if (cl == nt && row < N) {
                es[row * 8 + nt] = ps;
                ed[row * 8 + nt] = pd;
            }
        }
    }
}

__global__ __launch_bounds__(512) void k_scanH(int* __restrict__ H, int* __restrict__ BT) {
    __shared__ int sd[512];
    const int t = threadIdx.x;
    int* row = H + (size_t)blockIdx.x * ABLK;
    const int v = row[t];
    sd[t] = v;
    __syncthreads();
    for (int off = 1; off < 512; off <<= 1) {
        int add = (t >= off) ? sd[t - off] : 0;
        __syncthreads();
        sd[t] += add;
        __syncthreads();
    }
    row[t] = sd[t] - v;
    if (t == 511) BT[blockIdx.x] = sd[511];
}

__global__ __launch_bounds__(512) void k_scanBT(const int* __restrict__ BT,
                                                int* __restrict__ BB, int NBK) {
    __shared__ int sd[512];
    const int t = threadIdx.x;
    const int v = (t < NBK) ? BT[t] : 0;
    sd[t] = v;
    __syncthreads();
    for (int off = 1; off < 512; off <<= 1) {
        int add = (t >= off) ? sd[t - off] : 0;
        __syncthreads();
        sd[t] += add;
        __syncthreads();
    }
    if (t < NBK) BB[t] = sd[t] - v;
    if (t == 511) BB[NBK] = sd[511];
}

__global__ __launch_bounds__(256) void k_bscat(const int* __restrict__ ei, int E, int N,
                                               int NBK, const int* __restrict__ H,
                                               const int* __restrict__ BB,
                                               unsigned* __restrict__ E2) {
    __shared__ int cnt[512];
    __shared__ int base[512];
    const int t = threadIdx.x;
    for (int i = t; i < NBK; i += 256) {
        cnt[i] = 0;
        base[i] = BB[i] + H[(size_t)i * ABLK + blockIdx.x];
    }
    __syncthreads();
    const int Et = E + N;
    for (int e = blockIdx.x * 256 + t; e < Et; e += ABLK * 256) {
        int s, d;
        if (e < E) { s = ei[e]; d = ei[E + e]; }
        else       { s = e - E; d = e - E; }
        const int b = d >> SHIFT;
        const int r = atomicAdd(&cnt[b], 1);
        E2[base[b] + r] = (unsigned)s | ((unsigned)(d & 255) << 24);
    }
}

__global__ __launch_bounds__(256) void k_bcsr(const unsigned* __restrict__ E2,
                                              const int* __restrict__ BB, int N,
                                              int* __restrict__ deg,
                                              int* __restrict__ rowp,
                                              int* __restrict__ csr) {
    __shared__ int cnt[256];
    __shared__ int sc[256];
    __shared__ int rp[256];
    __shared__ int fl[256];
    const int t = threadIdx.x;
    const int b = blockIdx.x;
    const int lo = BB[b], hi = BB[b + 1];
    const int base_d = b << SHIFT;
    cnt[t] = 0; fl[t] = 0;
    __syncthreads();
    for (int i = lo + t; i < hi; i += 256)
        atomicAdd(&cnt[E2[i] >> 24], 1);
    __syncthreads();
    const int v = cnt[t];
    sc[t] = v;
    __syncthreads();
    for (int off = 1; off < 256; off <<= 1) {
        int add = (t >= off) ? sc[t - off] : 0;
        __syncthreads();
        sc[t] += add;
        __syncthreads();
    }
    rp[t] = sc[t] - v;
    const int d = base_d + t;
    if (d < N) { deg[d] = v; rowp[d] = lo + rp[t]; }
    __syncthreads();
    for (int i = lo + t; i < hi; i += 256) {
        const unsigned e = E2[i];
        const int ld = e >> 24;
        const int r = atomicAdd(&fl[ld], 1);
        csr[lo + rp[ld] + r] = (int)(e & 0xFFFFFFu);
    }
}

// -------- layer-1 aggregate: 8-edge tiles, full/tail split, bf16 h out ---------
__global__ __launch_bounds__(256) void k_l1(const unsigned short* __restrict__ xhb,
                                            const float* __restrict__ es,
                                            const float* __restrict__ ed,
                                            const int* __restrict__ rowp,
                                            const int* __restrict__ deg,
                                            const int* __restrict__ csr,
                                            const float* __restrict__ b1,
                                            unsigned short* __restrict__ hb, int N) {
    const int wave = threadIdx.x >> 6;
    const int lane = threadIdx.x & 63;
    const int n = blockIdx.x * 4 + wave;
    if (n >= N) return;
    const int hA = lane >> 3;
    const int eA = lane & 7;
    const float edv = ed[n * 8 + hA];
    const int start = rowp[n];
    const int cnt = deg[n];
    const int last = cnt - 1;
    const int lane4 = lane * 4;

    float acc0 = 0.f, acc1 = 0.f, dpart = 0.f;
    const char* xb = (const char*)xhb;

    const int full = cnt & ~7;
    int k = 0;
    for (; k < full; k += 8) {           // full tiles: no clamp, no zeroing
        const int s = csr[start + k + eA];
        const float a = lrelu_exp(es[s * 8 + hA] + edv);
        dpart += a;
        const int soff = s << 8;
#define L1E(e) { \
        const float ae = swz_f<SWZ(e)>(a); \
        const int   ro = swz_i<SWZ(e)>(soff); \
        const unsigned pv = *(const unsigned*)(xb + (unsigned)(ro + lane4)); \
        acc0 += ae * bf_lo(pv); \
        acc1 += ae * bf_hi(pv); }
        L1E(0) L1E(1) L1E(2) L1E(3) L1E(4) L1E(5) L1E(6) L1E(7)
#undef L1E
    }
    if (k < cnt) {                        // tail tile: wave-uniform skip
        const int ke = k + eA;
        const int idx = start + ((ke <= last) ? ke : last);
        const int s = csr[idx];
        const float a = (ke <= last) ? lrelu_exp(es[s * 8 + hA] + edv) : 0.f;
        dpart += a;
        const int soff = s << 8;
#define L1T(e) { \
        const float ae = swz_f<SWZ(e)>(a); \
        if (ae != 0.f) { \
            const int ro = swz_i<SWZ(e)>(soff); \
            const unsigned pv = *(const unsigned*)(xb + (unsigned)(ro + lane4)); \
            acc0 += ae * bf_lo(pv); \
            acc1 += ae * bf_hi(pv); } }
        L1T(0) L1T(1) L1T(2) L1T(3) L1T(4) L1T(5) L1T(6) L1T(7)
#undef L1T
    }
    dpart += __shfl_xor(dpart, 1, 64);
    dpart += __shfl_xor(dpart, 2, 64);
    dpart += __shfl_xor(dpart, 4, 64);

    const float inv = 1.f / (dpart + EPSF);
    const float2 bb = *(const float2*)(b1 + lane * 2);
    float o0 = acc0 * inv + bb.x;
    float o1 = acc1 * inv + bb.y;
    o0 = (o0 > 0.f) ? o0 : expm1f(o0);
    o1 = (o1 > 0.f) ? o1 : expm1f(o1);
    const unsigned pk = (unsigned)f2bf(o0) | ((unsigned)f2bf(o1) << 16);
    *(unsigned*)(hb + (size_t)n * 128 + lane * 2) = pk;
}

// ---- GEMM2 (MFMA) + fused e_src2/e_dst2 from f32 accumulators -----------------
__global__ __launch_bounds__(256) void k_mm2(const unsigned short* __restrict__ h,
                                             const unsigned short* __restrict__ W2s,
                                             const float* __restrict__ as2,
                                             const float* __restrict__ ad2,
                                             unsigned short* __restrict__ xh2,
                                             float* __restrict__ es2,
                                             float* __restrict__ ed2, int N) {
    __shared__ unsigned short Bs[12288];     // 24 KB
    const int t = threadIdx.x;
    for (int i = t; i < 1536; i += 256)
        ((uint4*)Bs)[i] = ((const uint4*)W2s)[i];

    const int wm = t >> 6;
    const int l  = t & 63;
    const int wrow0 = blockIdx.x * 64 + wm * 16;
    const int arow = wrow0 + (l & 15);
    const int rc = (arow < N) ? arow : (N - 1);

    short8 a[4];
    #pragma unroll
    for (int kt = 0; kt < 4; ++kt)
        a[kt] = *(const short8*)(h + (size_t)rc * 128 + kt * 32 + ((l >> 4) * 8));
    __syncthreads();

    f32x4 acc[3] = {};
    #pragma unroll
    for (int kt = 0; kt < 4; ++kt) {
        #pragma unroll
        for (int nt = 0; nt < 3; ++nt) {
            const short8 bh = *(const short8*)(Bs + (kt * 3 + nt) * 512 + l * 8);
            const short8 bl = *(const short8*)(Bs + 6144 + (kt * 3 + nt) * 512 + l * 8);
            acc[nt] = __builtin_amdgcn_mfma_f32_16x16x32_bf16(a[kt], bh, acc[nt], 0, 0, 0);
            acc[nt] = __builtin_amdgcn_mfma_f32_16x16x32_bf16(a[kt], bl, acc[nt], 0, 0, 0);
        }
    }

    const int cl = l & 15;
    const int g  = l >> 4;
    const int rbase = wrow0 + g * 4;
    #pragma unroll
    for (int reg = 0; reg < 4; ++reg) {
        const int orow = rbase + reg;
        if (orow < N) {
            #pragma unroll
            for (int nt = 0; nt < 3; ++nt) {
                const int c = nt * 16 + cl;
                if (c < 40)
                    xh2[(size_t)orow * 64 + c] = f2bf(acc[nt][reg]);
            }
        }
    }

    // fused e_src2/e_dst2 (single head): sum over all 40 cols
    const float a0 = as2[cl], d0 = ad2[cl];
    const float a1 = as2[16 + cl], d1 = ad2[16 + cl];
    const float a2 = (cl < 8) ? as2[32 + cl] : 0.f;
    const float d2 = (cl < 8) ? ad2[32 + cl] : 0.f;
    #pragma unroll
    for (int reg = 0; reg < 4; ++reg) {
        float ps = acc[0][reg] * a0 + acc[1][reg] * a1 + acc[2][reg] * a2;
        float pd = acc[0][reg] * d0 + acc[1][reg] * d1 + acc[2][reg] * d2;
        ps += __shfl_xor(ps, 1, 64); ps += __shfl_xor(ps, 2, 64);
        ps += __shfl_xor(ps, 4, 64); ps += __shfl_xor(ps, 8, 64);
        pd += __shfl_xor(pd, 1, 64); pd += __shfl_xor(pd, 2, 64);
        pd += __shfl_xor(pd, 4, 64); pd += __shfl_xor(pd, 8, 64);
        const int row = rbase + reg;
        if (cl == reg && row < N) {
            es2[row] = ps;
            ed2[row] = pd;
        }
    }
}

// ---- layer-2 aggregate: 2 nodes/wave, 4-edge tiles, bf16 padded rows ----------
__global__ __launch_bounds__(256) void k_l2(const unsigned short* __restrict__ xh2,
                                            const float* __restrict__ es2,
                                            const float* __restrict__ ed2,
                                            const int* __restrict__ rowp,
                                            const int* __restrict__ deg,
                                            const int* __restrict__ csr,
                                            const float* __restrict__ b2,
                                            float* __restrict__ out, int N) {
    const int wave = threadIdx.x >> 6;
    const int lane = threadIdx.x & 63;
    const int half = lane >> 5;
    const int n0 = blockIdx.x * 8 + wave * 2;
    if (n0 >= N) return;
    int n = n0 + half;
    const bool valid = (n < N);
    if (!valid) n = N - 1;
    const float edv = ed2[n];
    const int start = rowp[n];
    const int cnt = deg[n];
    const int last = cnt - 1;
    const int eA = lane & 3;
    const int c2 = lane & 31;
    const int cc4 = ((c2 < 20) ? c2 : 19) * 4;
    const char* xb = (const char*)xh2;
    const int cmax = max(cnt, __shfl_xor(cnt, 32, 64));

    float acc0 = 0.f, acc1 = 0.f, dpart = 0.f;
    for (int k = 0; k < cmax; k += 4) {
        const int ke = k + eA;
        const int idx = start + ((ke <= last) ? ke : last);
        const int s = csr[idx];
        const float a = (ke <= last) ? lrelu_exp(es2[s] + edv) : 0.f;
        dpart += a;
        const int soff = s << 7;
#define L2E(e) { \
        const float ae = swz_f<SWZ4(e)>(a); \
        const int   ro = swz_i<SWZ4(e)>(soff); \
        const unsigned pv = *(const unsigned*)(xb + (unsigned)(ro + cc4)); \
        acc0 += ae * bf_lo(pv); \
        acc1 += ae * bf_hi(pv); }
        L2E(0) L2E(1) L2E(2) L2E(3)
#undef L2E
    }
    dpart += __shfl_xor(dpart, 1, 64);
    dpart += __shfl_xor(dpart, 2, 64);

    if (valid && c2 < 20) {
        const float inv = 1.f / (dpart + EPSF);
        const float2 bb = *(const float2*)(b2 + c2 * 2);
        *(float2*)(out + (size_t)n * 40 + c2 * 2) =
            make_float2(acc0 * inv + bb.x, acc1 * inv + bb.y);
    }
}

extern "C" void kernel_launch(void* const* d_in, const int* in_sizes, int n_in,
                              void* d_out, int out_size, void* d_ws, size_t ws_size,
                              hipStream_t stream) {
    const float* x   = (const float*)d_in[0];
    const int*   ei  = (const int*)d_in[1];
    const float* W1  = (const float*)d_in[2];
    const float* as1 = (const float*)d_in[3];
    const float* ad1 = (const float*)d_in[4];
    const float* b1  = (const float*)d_in[5];
    const float* W2  = (const float*)d_in[6];
    const float* as2 = (const float*)d_in[7];
    const float* ad2 = (const float*)d_in[8];
    const float* b2  = (const float*)d_in[9];
    float* out = (float*)d_out;

    const int N   = in_sizes[0] / 128;
    const int E   = in_sizes[1] / 2;
    const int Et  = E + N;
    const int NBK = (N + 255) >> SHIFT;
    const int GBM = (N + 63) / 64;

    // ---- workspace layout ----
    char* p = (char*)d_ws;
    unsigned short* W1s = (unsigned short*)p; p += 32768 * 2;   // 64 KB
    unsigned short* W2s = (unsigned short*)p; p += 12288 * 2;   // 24 KB
    unsigned short* xhb = (unsigned short*)p; p += (size_t)N * 128 * 2;
    float* es1  = (float*)p; p += (size_t)N * 8 * 4;
    float* ed1  = (float*)p; p += (size_t)N * 8 * 4;
    int*   deg  = (int*)p;   p += (size_t)N * 4;
    int*   rowp = (int*)p;   p += (size_t)N * 4;
    int*   csr  = (int*)p;   p += (size_t)Et * 4;
    int*   H    = (int*)p;   p += (size_t)512 * ABLK * 4;
    int*   BT   = (int*)p;   p += 512 * 4;
    int*   BB   = (int*)p;   p += 512 * 4;
    unsigned short* hbuf = (unsigned short*)p; p += (size_t)N * 128 * 2;
    unsigned short* xh2  = (unsigned short*)p; p += (size_t)N * 64 * 2;
    unsigned* E2 = (unsigned*)hbuf;   // 6.8 MB < 25.6 MB; dead after k_bcsr
    float* es2 = es1;
    float* ed2 = ed1;

    k_ph    <<<ABLK + 88,       256, 0, stream>>>(ei, E, N, NBK, H, W1, W2, W1s, W2s);
    k_mm1   <<<GBM,             256, 0, stream>>>(x, W1s, as1, ad1, xhb, es1, ed1, N);
    k_scanH <<<NBK,             512, 0, stream>>>(H, BT);
    k_scanBT<<<1,               512, 0, stream>>>(BT, BB, NBK);
    k_bscat <<<ABLK,            256, 0, stream>>>(ei, E, N, NBK, H, BB, E2);
    k_bcsr  <<<NBK,             256, 0, stream>>>(E2, BB, N, deg, rowp, csr);
    k_l1    <<<(N + 3) / 4,     256, 0, stream>>>(xhb, es1, ed1, rowp, deg, csr, b1, hbuf, N);
    k_mm2   <<<GBM,             256, 0, stream>>>(hbuf, W2s, as2, ad2, xh2, es2, ed2, N);
    k_l2    <<<(N + 7) / 8,     256, 0, stream>>>(xh2, es2, ed2, rowp, deg, csr, b2, out, N);
}

// Round 11
// 219.248 us; speedup vs baseline: 1.1200x; 1.1200x over previous
//
#include <hip/hip_runtime.h>

#define NEG_SLOPE 0.2f
#define EPSF 1e-16f
#define ABLK 512
#define SHIFT 8
#define SWZ(e)  (((e) << 5) | 0x18)   // src = (lane&0x18)|e  (groups of 8)
#define SWZ4(e) (((e) << 5) | 0x1C)   // src = (lane&0x1C)|e  (groups of 4)

using short8 = __attribute__((ext_vector_type(8))) short;
using f32x4  = __attribute__((ext_vector_type(4))) float;

__device__ __forceinline__ float lrelu_exp(float a) {
    a = (a > 0.f) ? a : NEG_SLOPE * a;
    return __expf(a);
}

__device__ __forceinline__ unsigned short f2bf(float f) {   // RNE
    unsigned u = __float_as_uint(f);
    u += 0x7fff + ((u >> 16) & 1);
    return (unsigned short)(u >> 16);
}

__device__ __forceinline__ float bf2f(unsigned short b) {
    return __uint_as_float(((unsigned)b) << 16);
}

__device__ __forceinline__ float bf_lo(unsigned pv) { return __uint_as_float(pv << 16); }
__device__ __forceinline__ float bf_hi(unsigned pv) { return __uint_as_float(pv & 0xffff0000u); }

template <int PAT>
__device__ __forceinline__ float swz_f(float v) {
    return __uint_as_float((unsigned)__builtin_amdgcn_ds_swizzle(__float_as_int(v), PAT));
}
template <int PAT>
__device__ __forceinline__ int swz_i(int v) {
    return __builtin_amdgcn_ds_swizzle(v, PAT);
}

// ---- fused: bhist (blocks [0,ABLK)) + W-prep (blocks [ABLK, ABLK+88)) --------
__global__ __launch_bounds__(256) void k_ph(const int* __restrict__ ei, int E, int N,
                                            int NBK, int* __restrict__ H,
                                            const float* __restrict__ W1,
                                            const float* __restrict__ W2,
                                            unsigned short* __restrict__ W1s,
                                            unsigned short* __restrict__ W2s) {
    __shared__ int hist[512];
    const int t = threadIdx.x;
    if (blockIdx.x < ABLK) {
        for (int i = t; i < NBK; i += 256) hist[i] = 0;
        __syncthreads();
        const int Et = E + N;
        for (int e = blockIdx.x * 256 + t; e < Et; e += ABLK * 256) {
            int d = (e < E) ? ei[E + e] : (e - E);
            atomicAdd(&hist[d >> SHIFT], 1);
        }
        __syncthreads();
        for (int i = t; i < NBK; i += 256)
            H[(size_t)i * ABLK + blockIdx.x] = hist[i];
        return;
    }
    const int tid = (blockIdx.x - ABLK) * 256 + t;
    if (tid < 16384) {                       // W1: 4kt x 8nt x 64l x 8e
        const int e  = tid & 7;
        const int l  = (tid >> 3) & 63;
        const int nt = (tid >> 9) & 7;
        const int kt = tid >> 12;
        const int k  = kt * 32 + ((l >> 4) * 8) + e;
        const int n  = nt * 16 + (l & 15);
        const float w = W1[k * 128 + n];
        const unsigned short hi = f2bf(w);
        const unsigned short lo = f2bf(w - bf2f(hi));
        const int idx = (kt * 8 + nt) * 512 + l * 8 + e;
        W1s[idx] = hi;
        W1s[16384 + idx] = lo;
    } else {                                 // W2: 4kt x 3nt x 64l x 8e (pad n>=40)
        const int t2 = tid - 16384;
        if (t2 >= 6144) return;
        const int e  = t2 & 7;
        const int l  = (t2 >> 3) & 63;
        const int g  = t2 >> 9;
        const int nt = g % 3;
        const int kt = g / 3;
        const int k  = kt * 32 + ((l >> 4) * 8) + e;
        const int n  = nt * 16 + (l & 15);
        const float w = (n < 40) ? W2[k * 40 + n] : 0.f;
        const unsigned short hi = f2bf(w);
        const unsigned short lo = f2bf(w - bf2f(hi));
        const int idx = (kt * 3 + nt) * 512 + l * 8 + e;
        W2s[idx] = hi;
        W2s[6144 + idx] = lo;
    }
}

__global__ __launch_bounds__(512) void k_scanH(int* __restrict__ H, int* __restrict__ BT) {
    __shared__ int sd[512];
    const int t = threadIdx.x;
    int* row = H + (size_t)blockIdx.x * ABLK;
    const int v = row[t];
    sd[t] = v;
    __syncthreads();
    for (int off = 1; off < 512; off <<= 1) {
        int add = (t >= off) ? sd[t - off] : 0;
        __syncthreads();
        sd[t] += add;
        __syncthreads();
    }
    row[t] = sd[t] - v;
    if (t == 511) BT[blockIdx.x] = sd[511];
}

__global__ __launch_bounds__(512) void k_scanBT(const int* __restrict__ BT,
                                                int* __restrict__ BB, int NBK) {
    __shared__ int sd[512];
    const int t = threadIdx.x;
    const int v = (t < NBK) ? BT[t] : 0;
    sd[t] = v;
    __syncthreads();
    for (int off = 1; off < 512; off <<= 1) {
        int add = (t >= off) ? sd[t - off] : 0;
        __syncthreads();
        sd[t] += add;
        __syncthreads();
    }
    if (t < NBK) BB[t] = sd[t] - v;
    if (t == 511) BB[NBK] = sd[511];
}

// ---- fused: bscat (blocks [0,ABLK)) + GEMM1-MFMA (blocks [ABLK, ABLK+GBM)) ----
// Complementary pipes: bscat = LDS-atomic + scatter; mm1 = MFMA + LDS-read.
__global__ __launch_bounds__(256) void k_sm(const int* __restrict__ ei, int E, int N,
                                            int NBK, const int* __restrict__ H,
                                            const int* __restrict__ BB,
                                            unsigned* __restrict__ E2,
                                            const float* __restrict__ x,
                                            const unsigned short* __restrict__ W1s,
                                            unsigned short* __restrict__ xhb) {
    __shared__ unsigned short Bs[32768];     // 64 KB (mm1); bscat aliases 4 KB
    const int t = threadIdx.x;

    if (blockIdx.x < ABLK) {
        // ---------------- bscat ----------------
        int* cnt  = (int*)Bs;
        int* base = (int*)Bs + 512;
        for (int i = t; i < NBK; i += 256) {
            cnt[i] = 0;
            base[i] = BB[i] + H[(size_t)i * ABLK + blockIdx.x];
        }
        __syncthreads();
        const int Et = E + N;
        for (int e = blockIdx.x * 256 + t; e < Et; e += ABLK * 256) {
            int s, d;
            if (e < E) { s = ei[e]; d = ei[E + e]; }
            else       { s = e - E; d = e - E; }
            const int b = d >> SHIFT;
            const int r = atomicAdd(&cnt[b], 1);
            E2[base[b] + r] = (unsigned)s | ((unsigned)(d & 255) << 24);
        }
        return;
    }

    // ---------------- GEMM1 (MFMA bf16x3) ----------------
    for (int i = t; i < 4096; i += 256)
        ((uint4*)Bs)[i] = ((const uint4*)W1s)[i];

    const int wm = t >> 6;
    const int l  = t & 63;
    const int wrow0 = (blockIdx.x - ABLK) * 64 + wm * 16;
    const int arow = wrow0 + (l & 15);
    const int rc = (arow < N) ? arow : (N - 1);

    short8 ah[4], al[4];
    #pragma unroll
    for (int kt = 0; kt < 4; ++kt) {
        const float* xp = x + (size_t)rc * 128 + kt * 32 + ((l >> 4) * 8);
        const float4 v0 = ((const float4*)xp)[0];
        const float4 v1 = ((const float4*)xp)[1];
        const float vv[8] = {v0.x, v0.y, v0.z, v0.w, v1.x, v1.y, v1.z, v1.w};
        #pragma unroll
        for (int e = 0; e < 8; ++e) {
            const unsigned short hi = f2bf(vv[e]);
            ((unsigned short*)&ah[kt])[e] = hi;
            ((unsigned short*)&al[kt])[e] = f2bf(vv[e] - bf2f(hi));
        }
    }
    __syncthreads();

    f32x4 acc[8] = {};
    #pragma unroll
    for (int kt = 0; kt < 4; ++kt) {
        #pragma unroll
        for (int nt = 0; nt < 8; ++nt) {
            const short8 bh = *(const short8*)(Bs + (kt * 8 + nt) * 512 + l * 8);
            const short8 bl = *(const short8*)(Bs + 16384 + (kt * 8 + nt) * 512 + l * 8);
            acc[nt] = __builtin_amdgcn_mfma_f32_16x16x32_bf16(ah[kt], bh, acc[nt], 0, 0, 0);
            acc[nt] = __builtin_amdgcn_mfma_f32_16x16x32_bf16(ah[kt], bl, acc[nt], 0, 0, 0);
            acc[nt] = __builtin_amdgcn_mfma_f32_16x16x32_bf16(al[kt], bh, acc[nt], 0, 0, 0);
        }
    }

    const int cl = l & 15;
    const int rbase = wrow0 + ((l >> 4) * 4);
    #pragma unroll
    for (int reg = 0; reg < 4; ++reg) {
        const int orow = rbase + reg;
        if (orow < N) {
            #pragma unroll
            for (int nt = 0; nt < 8; ++nt)
                xhb[(size_t)orow * 128 + nt * 16 + cl] = f2bf(acc[nt][reg]);
        }
    }
}

// ---- fused: bcsr (blocks [0,NBK)) + esed1 (blocks [NBK, ...)) -----------------
__global__ __launch_bounds__(256) void k_ce(const unsigned* __restrict__ E2,
                                            const int* __restrict__ BB, int N,
                                            int* __restrict__ deg,
                                            int* __restrict__ rowp,
                                            int* __restrict__ csr, int NBK,
                                            const unsigned short* __restrict__ xhb,
                                            const float* __restrict__ asrc,
                                            const float* __restrict__ adst,
                                            float* __restrict__ es,
                                            float* __restrict__ ed) {
    __shared__ int cnt[256];
    __shared__ int sc[256];
    __shared__ int rp[256];
    __shared__ int fl[256];
    const int t = threadIdx.x;

    if (blockIdx.x >= NBK) {
        // ---------------- esed1 ----------------
        const int i = (blockIdx.x - NBK) * 256 + t;
        if (i >= N * 8) return;
        const int h = i & 7;
        const uint4* p = (const uint4*)(xhb + (size_t)i * 16);
        const uint4 q0 = p[0], q1 = p[1];
        const unsigned w[8] = {q0.x, q0.y, q0.z, q0.w, q1.x, q1.y, q1.z, q1.w};
        const float* av = asrc + h * 16;
        const float* bv = adst + h * 16;
        float s = 0.f, d = 0.f;
        #pragma unroll
        for (int j = 0; j < 8; ++j) {
            const float v0 = bf_lo(w[j]);
            const float v1 = bf_hi(w[j]);
            s += v0 * av[2 * j] + v1 * av[2 * j + 1];
            d += v0 * bv[2 * j] + v1 * bv[2 * j + 1];
        }
        es[i] = s; ed[i] = d;
        return;
    }

    // ---------------- bcsr ----------------
    const int b = blockIdx.x;
    const int lo = BB[b], hi = BB[b + 1];
    const int base_d = b << SHIFT;
    cnt[t] = 0; fl[t] = 0;
    __syncthreads();
    for (int i = lo + t; i < hi; i += 256)
        atomicAdd(&cnt[E2[i] >> 24], 1);
    __syncthreads();
    const int v = cnt[t];
    sc[t] = v;
    __syncthreads();
    for (int off = 1; off < 256; off <<= 1) {
        int add = (t >= off) ? sc[t - off] : 0;
        __syncthreads();
        sc[t] += add;
        __syncthreads();
    }
    rp[t] = sc[t] - v;
    const int d = base_d + t;
    if (d < N) { deg[d] = v; rowp[d] = lo + rp[t]; }
    __syncthreads();
    for (int i = lo + t; i < hi; i += 256) {
        const unsigned e = E2[i];
        const int ld = e >> 24;
        const int r = atomicAdd(&fl[ld], 1);
        csr[lo + rp[ld] + r] = (int)(e & 0xFFFFFFu);
    }
}

// -------- layer-1 aggregate: 8-edge tiles, 2-phase (R8 proven form) ------------
__global__ __launch_bounds__(256) void k_l1(const unsigned short* __restrict__ xhb,
                                            const float* __restrict__ es,
                                            const float* __restrict__ ed,
                                            const int* __restrict__ rowp,
                                            const int* __restrict__ deg,
                                            const int* __restrict__ csr,
                                            const float* __restrict__ b1,
                                            unsigned short* __restrict__ hb, int N) {
    const int wave = threadIdx.x >> 6;
    const int lane = threadIdx.x & 63;
    const int n = blockIdx.x * 4 + wave;
    if (n >= N) return;
    const int hA = lane >> 3;
    const int eA = lane & 7;
    const float edv = ed[n * 8 + hA];
    const int start = rowp[n];
    const int cnt = deg[n];
    const int last = cnt - 1;
    const int lane4 = lane * 4;

    float acc0 = 0.f, acc1 = 0.f, dpart = 0.f;
    const char* xb = (const char*)xhb;

    for (int k = 0; k < cnt; k += 8) {
        const int ke = k + eA;
        const int idx = start + min(ke, last);
        const int s = csr[idx];
        float a = lrelu_exp(es[s * 8 + hA] + edv);
        a = (ke <= last) ? a : 0.f;
        dpart += a;
        const int soff = s << 8;
#define L1E(e) { \
        const float ae = swz_f<SWZ(e)>(a); \
        const int   ro = swz_i<SWZ(e)>(soff); \
        const unsigned pv = *(const unsigned*)(xb + (unsigned)(ro + lane4)); \
        acc0 += ae * bf_lo(pv); \
        acc1 += ae * bf_hi(pv); }
        L1E(0) L1E(1) L1E(2) L1E(3) L1E(4) L1E(5) L1E(6) L1E(7)
#undef L1E
    }
    dpart += __shfl_xor(dpart, 1, 64);
    dpart += __shfl_xor(dpart, 2, 64);
    dpart += __shfl_xor(dpart, 4, 64);

    const float inv = 1.f / (dpart + EPSF);
    const float2 bb = *(const float2*)(b1 + lane * 2);
    float o0 = acc0 * inv + bb.x;
    float o1 = acc1 * inv + bb.y;
    o0 = (o0 > 0.f) ? o0 : expm1f(o0);
    o1 = (o1 > 0.f) ? o1 : expm1f(o1);
    const unsigned pk = (unsigned)f2bf(o0) | ((unsigned)f2bf(o1) << 16);
    *(unsigned*)(hb + (size_t)n * 128 + lane * 2) = pk;
}

// ---- GEMM2 (MFMA): xh2 = h @ W2 -> bf16 rows padded to 64 ushorts -------------
__global__ __launch_bounds__(256) void k_mm2(const unsigned short* __restrict__ h,
                                             const unsigned short* __restrict__ W2s,
                                             unsigned short* __restrict__ xh2, int N) {
    __shared__ unsigned short Bs[12288];     // 24 KB
    const int t = threadIdx.x;
    for (int i = t; i < 1536; i += 256)
        ((uint4*)Bs)[i] = ((const uint4*)W2s)[i];

    const int wm = t >> 6;
    const int l  = t & 63;
    const int wrow0 = blockIdx.x * 64 + wm * 16;
    const int arow = wrow0 + (l & 15);
    const int rc = (arow < N) ? arow : (N - 1);

    short8 a[4];
    #pragma unroll
    for (int kt = 0; kt < 4; ++kt)
        a[kt] = *(const short8*)(h + (size_t)rc * 128 + kt * 32 + ((l >> 4) * 8));
    __syncthreads();

    f32x4 acc[3] = {};
    #pragma unroll
    for (int kt = 0; kt < 4; ++kt) {
        #pragma unroll
        for (int nt = 0; nt < 3; ++nt) {
            const short8 bh = *(const short8*)(Bs + (kt * 3 + nt) * 512 + l * 8);
            const short8 bl = *(const short8*)(Bs + 6144 + (kt * 3 + nt) * 512 + l * 8);
            acc[nt] = __builtin_amdgcn_mfma_f32_16x16x32_bf16(a[kt], bh, acc[nt], 0, 0, 0);
            acc[nt] = __builtin_amdgcn_mfma_f32_16x16x32_bf16(a[kt], bl, acc[nt], 0, 0, 0);
        }
    }

    const int cl = l & 15;
    const int rbase = wrow0 + ((l >> 4) * 4);
    #pragma unroll
    for (int reg = 0; reg < 4; ++reg) {
        const int orow = rbase + reg;
        if (orow < N) {
            #pragma unroll
            for (int nt = 0; nt < 3; ++nt) {
                const int c = nt * 16 + cl;
                if (c < 40)
                    xh2[(size_t)orow * 64 + c] = f2bf(acc[nt][reg]);
            }
        }
    }
}

// ---- e_src2/e_dst2 from bf16 xh2: thread = node -------------------------------
__global__ __launch_bounds__(256) void k_esed2(const unsigned short* __restrict__ xh2,
                                               const float* __restrict__ as2,
                                               const float* __restrict__ ad2,
                                               float* __restrict__ es2,
                                               float* __restrict__ ed2, int N) {
    const int n = blockIdx.x * 256 + threadIdx.x;
    if (n >= N) return;
    const unsigned* p = (const unsigned*)(xh2 + (size_t)n * 64);
    float s = 0.f, d = 0.f;
    #pragma unroll
    for (int j = 0; j < 20; ++j) {
        const unsigned w = p[j];
        const float v0 = bf_lo(w);
        const float v1 = bf_hi(w);
        s += v0 * as2[2 * j] + v1 * as2[2 * j + 1];
        d += v0 * ad2[2 * j] + v1 * ad2[2 * j + 1];
    }
    es2[n] = s; ed2[n] = d;
}

// ---- layer-2 aggregate: 2 nodes/wave, 4-edge tiles, bf16 padded rows ----------
__global__ __launch_bounds__(256) void k_l2(const unsigned short* __restrict__ xh2,
                                            const float* __restrict__ es2,
                                            const float* __restrict__ ed2,
                                            const int* __restrict__ rowp,
                                            const int* __restrict__ deg,
                                            const int* __restrict__ csr,
                                            const float* __restrict__ b2,
                                            float* __restrict__ out, int N) {
    const int wave = threadIdx.x >> 6;
    const int lane = threadIdx.x & 63;
    const int half = lane >> 5;
    const int n0 = blockIdx.x * 8 + wave * 2;
    if (n0 >= N) return;
    int n = n0 + half;
    const bool valid = (n < N);
    if (!valid) n = N - 1;
    const float edv = ed2[n];
    const int start = rowp[n];
    const int cnt = deg[n];
    const int last = cnt - 1;
    const int eA = lane & 3;
    const int c2 = lane & 31;
    const int cc4 = ((c2 < 20) ? c2 : 19) * 4;
    const char* xb = (const char*)xh2;
    const int cmax = max(cnt, __shfl_xor(cnt, 32, 64));

    float acc0 = 0.f, acc1 = 0.f, dpart = 0.f;
    for (int k = 0; k < cmax; k += 4) {
        const int ke = k + eA;
        const int idx = start + ((ke <= last) ? ke : last);
        const int s = csr[idx];
        const float a = (ke <= last) ? lrelu_exp(es2[s] + edv) : 0.f;
        dpart += a;
        const int soff = s << 7;
#define L2E(e) { \
        const float ae = swz_f<SWZ4(e)>(a); \
        const int   ro = swz_i<SWZ4(e)>(soff); \
        const unsigned pv = *(const unsigned*)(xb + (unsigned)(ro + cc4)); \
        acc0 += ae * bf_lo(pv); \
        acc1 += ae * bf_hi(pv); }
        L2E(0) L2E(1) L2E(2) L2E(3)
#undef L2E
    }
    dpart += __shfl_xor(dpart, 1, 64);
    dpart += __shfl_xor(dpart, 2, 64);

    if (valid && c2 < 20) {
        const float inv = 1.f / (dpart + EPSF);
        const float2 bb = *(const float2*)(b2 + c2 * 2);
        *(float2*)(out + (size_t)n * 40 + c2 * 2) =
            make_float2(acc0 * inv + bb.x, acc1 * inv + bb.y);
    }
}

extern "C" void kernel_launch(void* const* d_in, const int* in_sizes, int n_in,
                              void* d_out, int out_size, void* d_ws, size_t ws_size,
                              hipStream_t stream) {
    const float* x   = (const float*)d_in[0];
    const int*   ei  = (const int*)d_in[1];
    const float* W1  = (const float*)d_in[2];
    const float* as1 = (const float*)d_in[3];
    const float* ad1 = (const float*)d_in[4];
    const float* b1  = (const float*)d_in[5];
    const float* W2  = (const float*)d_in[6];
    const float* as2 = (const float*)d_in[7];
    const float* ad2 = (const float*)d_in[8];
    const float* b2  = (const float*)d_in[9];
    float* out = (float*)d_out;

    const int N   = in_sizes[0] / 128;
    const int E   = in_sizes[1] / 2;
    const int Et  = E + N;
    const int NBK = (N + 255) >> SHIFT;
    const int GBM = (N + 63) / 64;
    const int EB1 = (N * 8 + 255) / 256;

    // ---- workspace layout ----
    char* p = (char*)d_ws;
    unsigned short* W1s = (unsigned short*)p; p += 32768 * 2;   // 64 KB
    unsigned short* W2s = (unsigned short*)p; p += 12288 * 2;   // 24 KB
    unsigned short* xhb = (unsigned short*)p; p += (size_t)N * 128 * 2;
    float* es1  = (float*)p; p += (size_t)N * 8 * 4;
    float* ed1  = (float*)p; p += (size_t)N * 8 * 4;
    int*   deg  = (int*)p;   p += (size_t)N * 4;
    int*   rowp = (int*)p;   p += (size_t)N * 4;
    int*   csr  = (int*)p;   p += (size_t)Et * 4;
    int*   H    = (int*)p;   p += (size_t)512 * ABLK * 4;
    int*   BT   = (int*)p;   p += 512 * 4;
    int*   BB   = (int*)p;   p += 512 * 4;
    unsigned short* hbuf = (unsigned short*)p; p += (size_t)N * 128 * 2;
    unsigned short* xh2  = (unsigned short*)p; p += (size_t)N * 64 * 2;
    unsigned* E2 = (unsigned*)hbuf;   // 6.8 MB < 25.6 MB; dead after k_ce
    float* es2 = es1;
    float* ed2 = ed1;

    k_ph    <<<ABLK + 88,       256, 0, stream>>>(ei, E, N, NBK, H, W1, W2, W1s, W2s);
    k_scanH <<<NBK,             512, 0, stream>>>(H, BT);
    k_scanBT<<<1,               512, 0, stream>>>(BT, BB, NBK);
    k_sm    <<<ABLK + GBM,      256, 0, stream>>>(ei, E, N, NBK, H, BB, E2, x, W1s, xhb);
    k_ce    <<<NBK + EB1,       256, 0, stream>>>(E2, BB, N, deg, rowp, csr, NBK,
                                                  xhb, as1, ad1, es1, ed1);
    k_l1    <<<(N + 3) / 4,     256, 0, stream>>>(xhb, es1, ed1, rowp, deg, csr, b1, hbuf, N);
    k_mm2   <<<GBM,             256, 0, stream>>>(hbuf, W2s, xh2, N);
    k_esed2 <<<(N + 255) / 256, 256, 0, stream>>>(xh2, as2, ad2, es2, ed2, N);
    k_l2    <<<(N + 7) / 8,     256, 0, stream>>>(xh2, es2, ed2, rowp, deg, csr, b2, out, N);
}